// Round 3
// baseline (332.113 us; speedup 1.0000x reference)
//
#include <hip/hip_runtime.h>
#include <hip/hip_bf16.h>

typedef __bf16 bf16_t;
typedef bf16_t bf16x8 __attribute__((ext_vector_type(8)));
typedef bf16_t bf16x4 __attribute__((ext_vector_type(4)));
typedef float  f32x4  __attribute__((ext_vector_type(4)));

#define LDC 104   // stride (bf16 elems) for 96-wide tiles
#define LDT 72    // stride for vT token dim
#define LDP 70    // stride for P token dim
#define LDG 392   // stride for 384-wide tiles (gbuf, fc2 weights)

// ws layout (bytes)
#define WS_WQ    0
#define WS_WK    19968
#define WS_WV    39936
#define WS_WP    59904
#define WS_FC1   79872      // [384][104] bf16
#define WS_FC2   159744     // [96][392] bf16
#define WS_BIAS  235008     // [3][64][64] f32 : 16*sigmoid(cpb bias)

__device__ __forceinline__ f32x4 mfma16(bf16x8 a, bf16x8 b, f32x4 c) {
    return __builtin_amdgcn_mfma_f32_16x16x32_bf16(a, b, c, 0, 0, 0);
}

__device__ __forceinline__ float cpbf(int v) {   // v in -7..7
    float x = (float)v * (8.0f / 7.0f);
    float l = log2f(fabsf(x) + 1.0f) * (1.0f / 3.0f);
    return x < 0.f ? -l : l;
}

__device__ __forceinline__ int regcnt(int t, int hw, int ww) {
    int r = t >> 3, c = t & 7;
    int rr = (hw == 31) ? (r < 4 ? 1 : 2) : 0;
    int cc = (ww == 31) ? (c < 4 ? 1 : 2) : 0;
    return rr * 3 + cc;
}

// ---------------- Kernel 0: CPB table + weight repack ----------------
__global__ __launch_bounds__(512) void k0_prep(
    const float* __restrict__ qw, const float* __restrict__ kw,
    const float* __restrict__ vw, const float* __restrict__ pw,
    const float* __restrict__ fc1w, const float* __restrict__ fc2w,
    const float* __restrict__ cw1, const float* __restrict__ cb1,
    const float* __restrict__ cw2, char* __restrict__ ws)
{
    int tid = threadIdx.x;
    if (blockIdx.x == 0) {
        __shared__ float part[450 * 3];
        __shared__ float table[225 * 3];
        if (tid < 450) {
            int pos = tid >> 1, half = tid & 1;
            int ia = pos / 15, ib = pos % 15;
            float c0 = cpbf(ia - 7), c1 = cpbf(ib - 7);
            float a0 = 0.f, a1 = 0.f, a2 = 0.f;
            int j0 = half * 256;
            for (int j = j0; j < j0 + 256; ++j) {
                float h = fmaf(c0, cw1[j], fmaf(c1, cw1[512 + j], cb1[j]));
                h = fmaxf(h, 0.f);
                a0 = fmaf(h, cw2[j * 3 + 0], a0);
                a1 = fmaf(h, cw2[j * 3 + 1], a1);
                a2 = fmaf(h, cw2[j * 3 + 2], a2);
            }
            part[tid * 3 + 0] = a0; part[tid * 3 + 1] = a1; part[tid * 3 + 2] = a2;
        }
        __syncthreads();
        if (tid < 225) {
            table[tid * 3 + 0] = part[(2 * tid) * 3 + 0] + part[(2 * tid + 1) * 3 + 0];
            table[tid * 3 + 1] = part[(2 * tid) * 3 + 1] + part[(2 * tid + 1) * 3 + 1];
            table[tid * 3 + 2] = part[(2 * tid) * 3 + 2] + part[(2 * tid + 1) * 3 + 2];
        }
        __syncthreads();
        float* bias = (float*)(ws + WS_BIAS);
        for (int e = tid; e < 3 * 64 * 64; e += 512) {
            int h = e >> 12, nm = e & 4095, n = nm >> 6, m = nm & 63;
            int dr = (n >> 3) - (m >> 3) + 7, dc = (n & 7) - (m & 7) + 7;
            float t = table[(dr * 15 + dc) * 3 + h];
            bias[e] = 16.f / (1.f + __expf(-t));
        }
    } else {
        int rid = (blockIdx.x - 1) * 512 + tid;      // 0..27647, float4-coalesced reads
        if (rid < 9216) {                            // q,k,v,proj: [96 in][96 out] -> [out][in]
            int which = rid / 2304, r = rid % 2304;
            int i = r / 24, o4 = r % 24;
            const float* src = which == 0 ? qw : which == 1 ? kw : which == 2 ? vw : pw;
            float4 u = *(const float4*)(src + i * 96 + 4 * o4);
            bf16_t* dst = (bf16_t*)(ws + WS_WQ + which * 19968);
            dst[(4 * o4 + 0) * LDC + i] = (bf16_t)u.x;
            dst[(4 * o4 + 1) * LDC + i] = (bf16_t)u.y;
            dst[(4 * o4 + 2) * LDC + i] = (bf16_t)u.z;
            dst[(4 * o4 + 3) * LDC + i] = (bf16_t)u.w;
        } else if (rid < 18432) {                    // fc1: [96][384] -> [384][104]
            int r = rid - 9216;
            int i = r / 96, m4 = r % 96;
            float4 u = *(const float4*)(fc1w + i * 384 + 4 * m4);
            bf16_t* dst = (bf16_t*)(ws + WS_FC1);
            dst[(4 * m4 + 0) * LDC + i] = (bf16_t)u.x;
            dst[(4 * m4 + 1) * LDC + i] = (bf16_t)u.y;
            dst[(4 * m4 + 2) * LDC + i] = (bf16_t)u.z;
            dst[(4 * m4 + 3) * LDC + i] = (bf16_t)u.w;
        } else {                                     // fc2: [384][96] -> [96][392]
            int r = rid - 18432;
            int g = r / 24, o4 = r % 24;
            float4 u = *(const float4*)(fc2w + g * 96 + 4 * o4);
            bf16_t* dst = (bf16_t*)(ws + WS_FC2);
            dst[(4 * o4 + 0) * LDG + g] = (bf16_t)u.x;
            dst[(4 * o4 + 1) * LDG + g] = (bf16_t)u.y;
            dst[(4 * o4 + 2) * LDG + g] = (bf16_t)u.z;
            dst[(4 * o4 + 3) * LDG + g] = (bf16_t)u.w;
        }
    }
}

// ---------------- Kernel A: fused window attention -> hs (into d_out) ----------------
// LDS 40704 -> 4 blocks/CU. 5 barriers. A-frags of x gathered直接 from global.
__global__ __launch_bounds__(256, 4) void kA_attn(
    const float* __restrict__ hidden, const float* __restrict__ tv,
    const float* __restrict__ qb, const float* __restrict__ vb,
    const float* __restrict__ pb, const float* __restrict__ lsc,
    const float* __restrict__ lnww, const float* __restrict__ lnwb,
    const float* __restrict__ lnbw, const float* __restrict__ lnbb,
    const char* __restrict__ ws, float* __restrict__ hs)
{
    __shared__ __align__(16) char sm[40704];
    bf16_t* vT   = (bf16_t*)(sm + 0);         // [96][72]   = 13824
    bf16_t* qn   = (bf16_t*)(sm + 13824);     // [64][104]  = 13312
    bf16_t* kn   = (bf16_t*)(sm + 27136);     // [64][104]  = 13312 (end 40448)
    bf16_t* P    = (bf16_t*)(sm + 13824);     // [3][64][70] = 26880, overlays qn+kn (after B2)
    bf16_t* ctxb = (bf16_t*)(sm + 0);         // [64][104], overlays vT (after B4)

    const int tid = threadIdx.x;
    const int wv = tid >> 6, lane = tid & 63, lg = lane >> 4, lr = lane & 15;
    const int wid = blockIdx.x;
    const int bat = wid >> 10, wim = wid & 1023, hw = wim >> 5, wwi = wim & 31;

    // ---- phase 1: QKV; A-frags gathered from global (rolled window), B-frags from ws ----
    {
        bf16x8 af[3];
        {
            int tok = 16 * wv + lr;
            int gr = ((hw << 3) + (tok >> 3) + 4) & 255;
            int gc = ((wwi << 3) + (tok & 7) + 4) & 255;
            const float* xb = hidden + (((size_t)bat << 16) + (gr << 8) + gc) * 96;
            #pragma unroll
            for (int ks = 0; ks < 3; ++ks) {
                float4 u0 = *(const float4*)(xb + 32 * ks + 8 * lg);
                float4 u1 = *(const float4*)(xb + 32 * ks + 8 * lg + 4);
                bf16x8 f;
                f[0] = (bf16_t)u0.x; f[1] = (bf16_t)u0.y; f[2] = (bf16_t)u0.z; f[3] = (bf16_t)u0.w;
                f[4] = (bf16_t)u1.x; f[5] = (bf16_t)u1.y; f[6] = (bf16_t)u1.z; f[7] = (bf16_t)u1.w;
                af[ks] = f;
            }
        }
        const bf16_t* Wq = (const bf16_t*)(ws + WS_WQ);
        const bf16_t* Wk = (const bf16_t*)(ws + WS_WK);
        const bf16_t* Wv = (const bf16_t*)(ws + WS_WV);

        #pragma unroll
        for (int h = 0; h < 3; ++h) {        // Q per head (bias, then cosine-normalize)
            f32x4 a0 = {0.f,0.f,0.f,0.f}, a1 = {0.f,0.f,0.f,0.f};
            #pragma unroll
            for (int ks = 0; ks < 3; ++ks) {
                a0 = mfma16(af[ks], *(const bf16x8*)(Wq + (32 * h + lr) * LDC + 32 * ks + 8 * lg), a0);
                a1 = mfma16(af[ks], *(const bf16x8*)(Wq + (32 * h + 16 + lr) * LDC + 32 * ks + 8 * lg), a1);
            }
            float b0 = qb[32 * h + lr], b1 = qb[32 * h + 16 + lr];
            #pragma unroll
            for (int j = 0; j < 4; ++j) { a0[j] += b0; a1[j] += b1; }
            #pragma unroll
            for (int j = 0; j < 4; ++j) {
                float s = a0[j] * a0[j] + a1[j] * a1[j];
                s += __shfl_xor(s, 1); s += __shfl_xor(s, 2); s += __shfl_xor(s, 4); s += __shfl_xor(s, 8);
                float inv = 1.f / fmaxf(sqrtf(s), 1e-12f);
                int row = 16 * wv + 4 * lg + j;
                qn[row * LDC + 32 * h + lr]      = (bf16_t)(a0[j] * inv);
                qn[row * LDC + 32 * h + 16 + lr] = (bf16_t)(a1[j] * inv);
            }
        }
        #pragma unroll
        for (int h = 0; h < 3; ++h) {        // K per head (no bias, normalize)
            f32x4 a0 = {0.f,0.f,0.f,0.f}, a1 = {0.f,0.f,0.f,0.f};
            #pragma unroll
            for (int ks = 0; ks < 3; ++ks) {
                a0 = mfma16(af[ks], *(const bf16x8*)(Wk + (32 * h + lr) * LDC + 32 * ks + 8 * lg), a0);
                a1 = mfma16(af[ks], *(const bf16x8*)(Wk + (32 * h + 16 + lr) * LDC + 32 * ks + 8 * lg), a1);
            }
            #pragma unroll
            for (int j = 0; j < 4; ++j) {
                float s = a0[j] * a0[j] + a1[j] * a1[j];
                s += __shfl_xor(s, 1); s += __shfl_xor(s, 2); s += __shfl_xor(s, 4); s += __shfl_xor(s, 8);
                float inv = 1.f / fmaxf(sqrtf(s), 1e-12f);
                int row = 16 * wv + 4 * lg + j;
                kn[row * LDC + 32 * h + lr]      = (bf16_t)(a0[j] * inv);
                kn[row * LDC + 32 * h + 16 + lr] = (bf16_t)(a1[j] * inv);
            }
        }
        #pragma unroll
        for (int nt = 0; nt < 6; ++nt) {     // V (+bias), store transposed
            f32x4 a = {0.f,0.f,0.f,0.f};
            #pragma unroll
            for (int ks = 0; ks < 3; ++ks)
                a = mfma16(af[ks], *(const bf16x8*)(Wv + (16 * nt + lr) * LDC + 32 * ks + 8 * lg), a);
            float bv_ = vb[16 * nt + lr];
            bf16x4 pk;
            #pragma unroll
            for (int j = 0; j < 4; ++j) pk[j] = (bf16_t)(a[j] + bv_);
            *(bf16x4*)(vT + (16 * nt + lr) * LDT + 16 * wv + 4 * lg) = pk;
        }
    }
    __syncthreads();                                         // B1

    // ---- phase 2: S = qn@kn^T (+bias+mask), softmax, write P ----
    {
        f32x4 s[3][4];
        #pragma unroll
        for (int h = 0; h < 3; ++h) {
            bf16x8 aq = *(const bf16x8*)(qn + (16 * wv + lr) * LDC + 32 * h + 8 * lg);
            bf16x8 bk[4];
            #pragma unroll
            for (int f = 0; f < 4; ++f)
                bk[f] = *(const bf16x8*)(kn + (16 * f + lr) * LDC + 32 * h + 8 * lg);
            #pragma unroll
            for (int f = 0; f < 4; ++f) {
                f32x4 z = {0.f,0.f,0.f,0.f};
                s[h][f] = mfma16(aq, bk[f], z);
            }
        }
        __syncthreads();                                     // B2: qn/kn reads done, P may overlay

        float ls[3];
        #pragma unroll
        for (int h = 0; h < 3; ++h) ls[h] = __expf(fminf(lsc[h], 4.6051702f));
        const float* biasT = (const float*)(ws + WS_BIAS);
        int cntm[4], cnti[4];
        #pragma unroll
        for (int f = 0; f < 4; ++f) cntm[f] = regcnt(16 * f + lr, hw, wwi);
        #pragma unroll
        for (int j = 0; j < 4; ++j) cnti[j] = regcnt(16 * wv + 4 * lg + j, hw, wwi);
        #pragma unroll
        for (int h = 0; h < 3; ++h) {
            #pragma unroll
            for (int f = 0; f < 4; ++f)
                #pragma unroll
                for (int j = 0; j < 4; ++j) {
                    float b = biasT[(h << 12) + (16 * wv + 4 * lg + j) * 64 + 16 * f + lr];
                    float mk = (cnti[j] != cntm[f]) ? -100.f : 0.f;
                    s[h][f][j] = fmaf(s[h][f][j], ls[h], b + mk);
                }
            #pragma unroll
            for (int j = 0; j < 4; ++j) {
                float mx = fmaxf(fmaxf(s[h][0][j], s[h][1][j]), fmaxf(s[h][2][j], s[h][3][j]));
                mx = fmaxf(mx, __shfl_xor(mx, 1)); mx = fmaxf(mx, __shfl_xor(mx, 2));
                mx = fmaxf(mx, __shfl_xor(mx, 4)); mx = fmaxf(mx, __shfl_xor(mx, 8));
                float sum = 0.f;
                #pragma unroll
                for (int f = 0; f < 4; ++f) { float e = __expf(s[h][f][j] - mx); s[h][f][j] = e; sum += e; }
                sum += __shfl_xor(sum, 1); sum += __shfl_xor(sum, 2); sum += __shfl_xor(sum, 4); sum += __shfl_xor(sum, 8);
                float inv = 1.f / sum;
                int row = 16 * wv + 4 * lg + j;
                #pragma unroll
                for (int f = 0; f < 4; ++f)
                    P[h * 64 * LDP + row * LDP + 16 * f + lr] = (bf16_t)(s[h][f][j] * inv);
            }
        }
    }
    __syncthreads();                                         // B3: P written

    // ---- phase 3: ctx = P@V ----
    {
        f32x4 ctx[6];
        #pragma unroll
        for (int t = 0; t < 6; ++t) { f32x4 z = {0.f,0.f,0.f,0.f}; ctx[t] = z; }
        #pragma unroll
        for (int h = 0; h < 3; ++h) {
            bf16x8 ap[2], bv2[2][2];
            #pragma unroll
            for (int ks = 0; ks < 2; ++ks) {
                ap[ks] = *(const bf16x8*)(P + h * 64 * LDP + (16 * wv + lr) * LDP + 32 * ks + 8 * lg);
                #pragma unroll
                for (int dt = 0; dt < 2; ++dt)
                    bv2[dt][ks] = *(const bf16x8*)(vT + (32 * h + 16 * dt + lr) * LDT + 32 * ks + 8 * lg);
            }
            #pragma unroll
            for (int ks = 0; ks < 2; ++ks)
                #pragma unroll
                for (int dt = 0; dt < 2; ++dt)
                    ctx[2 * h + dt] = mfma16(ap[ks], bv2[dt][ks], ctx[2 * h + dt]);
        }
        __syncthreads();                                     // B4: all P/vT reads done
        #pragma unroll
        for (int t = 0; t < 6; ++t)
            #pragma unroll
            for (int j = 0; j < 4; ++j)
                ctxb[(16 * wv + 4 * lg + j) * LDC + 16 * t + lr] = (bf16_t)ctx[t][j];
    }
    __syncthreads();                                         // B5

    // ---- phase 4: proj (B from global) + conditional LN + residual -> hs ----
    {
        const bf16_t* Wp = (const bf16_t*)(ws + WS_WP);
        bf16x8 af[3];
        #pragma unroll
        for (int ks = 0; ks < 3; ++ks) af[ks] = *(const bf16x8*)(ctxb + (16 * wv + lr) * LDC + 32 * ks + 8 * lg);
        f32x4 acc[6];
        #pragma unroll
        for (int nt = 0; nt < 6; ++nt) {
            f32x4 a = {0.f,0.f,0.f,0.f};
            #pragma unroll
            for (int ks = 0; ks < 3; ++ks)
                a = mfma16(af[ks], *(const bf16x8*)(Wp + (16 * nt + lr) * LDC + 32 * ks + 8 * lg), a);
            float bp = pb[16 * nt + lr];
            #pragma unroll
            for (int j = 0; j < 4; ++j) a[j] += bp;
            acc[nt] = a;
        }
        float tb = tv[bat];
        #pragma unroll
        for (int j = 0; j < 4; ++j) {
            float smn = 0.f, sq = 0.f;
            #pragma unroll
            for (int t = 0; t < 6; ++t) { float v = acc[t][j]; smn += v; sq = fmaf(v, v, sq); }
            smn += __shfl_xor(smn, 1); smn += __shfl_xor(smn, 2); smn += __shfl_xor(smn, 4); smn += __shfl_xor(smn, 8);
            sq  += __shfl_xor(sq, 1);  sq  += __shfl_xor(sq, 2);  sq  += __shfl_xor(sq, 4);  sq  += __shfl_xor(sq, 8);
            float mean = smn * (1.f / 96.f);
            float var  = sq * (1.f / 96.f) - mean * mean;
            float rstd = rsqrtf(var + 1e-5f);
            int trow = 16 * wv + 4 * lg + j;
            int gr = ((hw << 3) + (trow >> 3) + 4) & 255;
            int gc = ((wwi << 3) + (trow & 7) + 4) & 255;
            size_t gbase = (((size_t)bat << 16) + (gr << 8) + gc) * 96;
            #pragma unroll
            for (int t = 0; t < 6; ++t) {
                int col = 16 * t + lr;
                float w = fmaf(tb, lnww[col], lnwb[col]);
                float b = fmaf(tb, lnbw[col], lnbb[col]);
                float xn = (acc[t][j] - mean) * rstd;
                hs[gbase + col] = hidden[gbase + col] + fmaf(w, xn, b);
            }
        }
    }
}

// ---------------- Kernel B: MLP + conditional LN + residual (in-place on d_out) ----------------
// Full-384 intermediate per wave: 1 barrier total. LDS 50176 -> 3 blocks/CU.
__global__ __launch_bounds__(256, 3) void kB_mlp(
    const float* __restrict__ tv, const float* __restrict__ fc1b,
    const float* __restrict__ fc2b,
    const float* __restrict__ lnww, const float* __restrict__ lnwb,
    const float* __restrict__ lnbw, const float* __restrict__ lnbb,
    const char* __restrict__ ws, float* __restrict__ io)
{
    __shared__ __align__(16) bf16_t gbuf[64 * LDG];   // 50176 B

    const int tid = threadIdx.x;
    const int wv = tid >> 6, lane = tid & 63, lg = lane >> 4, lr = lane & 15;
    const size_t t0 = (size_t)blockIdx.x * 64;

    // A-fragments of hs directly from global (f32 -> bf16)
    bf16x8 hf[3];
    #pragma unroll
    for (int ks = 0; ks < 3; ++ks) {
        const float* p = io + (t0 + 16 * wv + lr) * 96 + 32 * ks + 8 * lg;
        float4 u0 = *(const float4*)p;
        float4 u1 = *(const float4*)(p + 4);
        bf16x8 f;
        f[0] = (bf16_t)u0.x; f[1] = (bf16_t)u0.y; f[2] = (bf16_t)u0.z; f[3] = (bf16_t)u0.w;
        f[4] = (bf16_t)u1.x; f[5] = (bf16_t)u1.y; f[6] = (bf16_t)u1.z; f[7] = (bf16_t)u1.w;
        hf[ks] = f;
    }

    const bf16_t* w1 = (const bf16_t*)(ws + WS_FC1);
    const bf16_t* w2 = (const bf16_t*)(ws + WS_FC2);

    // fc1 + gelu, all 24 output tiles (no chunking, acc released per tile)
    #pragma unroll 6
    for (int nt = 0; nt < 24; ++nt) {
        f32x4 a = {0.f,0.f,0.f,0.f};
        #pragma unroll
        for (int ks = 0; ks < 3; ++ks)
            a = mfma16(hf[ks], *(const bf16x8*)(w1 + (16 * nt + lr) * LDC + 32 * ks + 8 * lg), a);
        float bb = fc1b[16 * nt + lr];
        #pragma unroll
        for (int j = 0; j < 4; ++j) {
            float x = a[j] + bb;
            // tanh-form GELU: x - x/(e^{2u}+1), u = 0.79788456(x + 0.044715 x^3)
            float u = 0.7978845608f * fmaf(0.044715f * x, x * x, x);
            float t = __expf(2.f * u);
            float g = x - x * __builtin_amdgcn_rcpf(t + 1.f);
            gbuf[(16 * wv + 4 * lg + j) * LDG + 16 * nt + lr] = (bf16_t)g;
        }
    }
    __syncthreads();                                  // the ONLY barrier

    // fc2 over 12 k-steps
    f32x4 mlp[6];
    #pragma unroll
    for (int t = 0; t < 6; ++t) { f32x4 z = {0.f,0.f,0.f,0.f}; mlp[t] = z; }
    #pragma unroll
    for (int kk = 0; kk < 12; ++kk) {
        bf16x8 gf = *(const bf16x8*)(gbuf + (16 * wv + lr) * LDG + 32 * kk + 8 * lg);
        #pragma unroll
        for (int nt = 0; nt < 6; ++nt)
            mlp[nt] = mfma16(gf, *(const bf16x8*)(w2 + (16 * nt + lr) * LDG + 32 * kk + 8 * lg), mlp[nt]);
    }

    float tb = tv[t0 >> 16];
    #pragma unroll
    for (int nt = 0; nt < 6; ++nt) {
        float bb = fc2b[16 * nt + lr];
        #pragma unroll
        for (int j = 0; j < 4; ++j) mlp[nt][j] += bb;
    }
    #pragma unroll
    for (int j = 0; j < 4; ++j) {
        float smn = 0.f, sq = 0.f;
        #pragma unroll
        for (int t = 0; t < 6; ++t) { float v = mlp[t][j]; smn += v; sq = fmaf(v, v, sq); }
        smn += __shfl_xor(smn, 1); smn += __shfl_xor(smn, 2); smn += __shfl_xor(smn, 4); smn += __shfl_xor(smn, 8);
        sq  += __shfl_xor(sq, 1);  sq  += __shfl_xor(sq, 2);  sq  += __shfl_xor(sq, 4);  sq  += __shfl_xor(sq, 8);
        float mean = smn * (1.f / 96.f);
        float var  = sq * (1.f / 96.f) - mean * mean;
        float rstd = rsqrtf(var + 1e-5f);
        size_t row = t0 + 16 * wv + 4 * lg + j;
        #pragma unroll
        for (int t = 0; t < 6; ++t) {
            int col = 16 * t + lr;
            float w = fmaf(tb, lnww[col], lnwb[col]);
            float b = fmaf(tb, lnbw[col], lnbb[col]);
            float xn = (mlp[t][j] - mean) * rstd;
            io[row * 96 + col] = io[row * 96 + col] + fmaf(w, xn, b);
        }
    }
}

extern "C" void kernel_launch(void* const* d_in, const int* in_sizes, int n_in,
                              void* d_out, int out_size, void* d_ws, size_t ws_size,
                              hipStream_t stream)
{
    const float* hidden = (const float*)d_in[0];
    const float* tv     = (const float*)d_in[1];
    const float* q_w    = (const float*)d_in[2];
    const float* q_b    = (const float*)d_in[3];
    const float* k_w    = (const float*)d_in[4];
    const float* v_w    = (const float*)d_in[5];
    const float* v_b    = (const float*)d_in[6];
    const float* p_w    = (const float*)d_in[7];
    const float* p_b    = (const float*)d_in[8];
    const float* lsc    = (const float*)d_in[9];
    const float* cw1    = (const float*)d_in[10];
    const float* cb1    = (const float*)d_in[11];
    const float* cw2    = (const float*)d_in[12];
    const float* lnb_ww = (const float*)d_in[13];
    const float* lnb_wb = (const float*)d_in[14];
    const float* lnb_bw = (const float*)d_in[15];
    const float* lnb_bb = (const float*)d_in[16];
    const float* lna_ww = (const float*)d_in[17];
    const float* lna_wb = (const float*)d_in[18];
    const float* lna_bw = (const float*)d_in[19];
    const float* lna_bb = (const float*)d_in[20];
    const float* fc1_w  = (const float*)d_in[21];
    const float* fc1_b  = (const float*)d_in[22];
    const float* fc2_w  = (const float*)d_in[23];
    const float* fc2_b  = (const float*)d_in[24];
    char* ws = (char*)d_ws;
    float* out = (float*)d_out;

    k0_prep<<<dim3(55), dim3(512), 0, stream>>>(q_w, k_w, v_w, p_w, fc1_w, fc2_w, cw1, cb1, cw2, ws);
    kA_attn<<<dim3(2048), dim3(256), 0, stream>>>(hidden, tv, q_b, v_b, p_b, lsc,
                                                  lnb_ww, lnb_wb, lnb_bw, lnb_bb, ws, out);
    kB_mlp<<<dim3(2048), dim3(256), 0, stream>>>(tv, fc1_b, fc2_b,
                                                 lna_ww, lna_wb, lna_bw, lna_bb, ws, out);
}

// Round 4
// 284.482 us; speedup vs baseline: 1.1674x; 1.1674x over previous
//
#include <hip/hip_runtime.h>
#include <hip/hip_bf16.h>

typedef __bf16 bf16_t;
typedef bf16_t bf16x8 __attribute__((ext_vector_type(8)));
typedef bf16_t bf16x4 __attribute__((ext_vector_type(4)));
typedef float  f32x4  __attribute__((ext_vector_type(4)));

#define LDC 104   // stride (bf16 elems) for 96-wide tiles
#define LDT 72    // stride for vT token dim
#define LDP 70    // stride for P token dim
#define LDG 392   // stride for 384-wide tiles (gbuf, fc2 weights)

// ws layout (bytes)
#define WS_WQ    0
#define WS_WK    19968
#define WS_WV    39936
#define WS_WP    59904
#define WS_FC1   79872      // [384][104] bf16
#define WS_FC2   159744     // [96][392] bf16
#define WS_BIAS  235008     // [3][64][64] f32 : 16*sigmoid(cpb bias)
#define WS_TBL   284160     // [225][3] f32 raw cpb table

__device__ __forceinline__ f32x4 mfma16(bf16x8 a, bf16x8 b, f32x4 c) {
    return __builtin_amdgcn_mfma_f32_16x16x32_bf16(a, b, c, 0, 0, 0);
}

__device__ __forceinline__ float cpbf(int v) {   // v in -7..7
    float x = (float)v * (8.0f / 7.0f);
    float l = log2f(fabsf(x) + 1.0f) * (1.0f / 3.0f);
    return x < 0.f ? -l : l;
}

__device__ __forceinline__ int regcnt(int t, int hw, int ww) {
    int r = t >> 3, c = t & 7;
    int rr = (hw == 31) ? (r < 4 ? 1 : 2) : 0;
    int cc = (ww == 31) ? (c < 4 ? 1 : 2) : 0;
    return rr * 3 + cc;
}

// ---------------- k0a: CPB table — one WAVE per entry, lanes parallel over 512 ----------------
__global__ __launch_bounds__(256) void k0a_cpb(
    const float* __restrict__ cw1, const float* __restrict__ cb1,
    const float* __restrict__ cw2, char* __restrict__ ws)
{
    const int wv = threadIdx.x >> 6, lane = threadIdx.x & 63;
    const int e = blockIdx.x * 4 + wv;
    if (e >= 225) return;
    int ia = e / 15, ib = e % 15;
    float c0 = cpbf(ia - 7), c1 = cpbf(ib - 7);
    float a0 = 0.f, a1 = 0.f, a2 = 0.f;
    #pragma unroll
    for (int c = 0; c < 8; ++c) {
        int j = c * 64 + lane;
        float h = fmaf(c0, cw1[j], fmaf(c1, cw1[512 + j], cb1[j]));
        h = fmaxf(h, 0.f);
        a0 = fmaf(h, cw2[j * 3 + 0], a0);
        a1 = fmaf(h, cw2[j * 3 + 1], a1);
        a2 = fmaf(h, cw2[j * 3 + 2], a2);
    }
    #pragma unroll
    for (int m = 1; m < 64; m <<= 1) {
        a0 += __shfl_xor(a0, m);
        a1 += __shfl_xor(a1, m);
        a2 += __shfl_xor(a2, m);
    }
    if (lane == 0) {
        float* tbl = (float*)(ws + WS_TBL);
        tbl[e * 3 + 0] = a0; tbl[e * 3 + 1] = a1; tbl[e * 3 + 2] = a2;
    }
}

// ---------------- k0w: weight repack (blocks 0..53) + bias expand (blocks 54..77) ----------------
__global__ __launch_bounds__(512) void k0w_prep(
    const float* __restrict__ qw, const float* __restrict__ kw,
    const float* __restrict__ vw, const float* __restrict__ pw,
    const float* __restrict__ fc1w, const float* __restrict__ fc2w,
    char* __restrict__ ws)
{
    int tid = threadIdx.x;
    if (blockIdx.x < 54) {
        int rid = blockIdx.x * 512 + tid;            // 0..27647, float4-coalesced reads
        if (rid < 9216) {                            // q,k,v,proj: [96 in][96 out] -> [out][in]
            int which = rid / 2304, r = rid % 2304;
            int i = r / 24, o4 = r % 24;
            const float* src = which == 0 ? qw : which == 1 ? kw : which == 2 ? vw : pw;
            float4 u = *(const float4*)(src + i * 96 + 4 * o4);
            bf16_t* dst = (bf16_t*)(ws + WS_WQ + which * 19968);
            dst[(4 * o4 + 0) * LDC + i] = (bf16_t)u.x;
            dst[(4 * o4 + 1) * LDC + i] = (bf16_t)u.y;
            dst[(4 * o4 + 2) * LDC + i] = (bf16_t)u.z;
            dst[(4 * o4 + 3) * LDC + i] = (bf16_t)u.w;
        } else if (rid < 18432) {                    // fc1: [96][384] -> [384][104]
            int r = rid - 9216;
            int i = r / 96, m4 = r % 96;
            float4 u = *(const float4*)(fc1w + i * 384 + 4 * m4);
            bf16_t* dst = (bf16_t*)(ws + WS_FC1);
            dst[(4 * m4 + 0) * LDC + i] = (bf16_t)u.x;
            dst[(4 * m4 + 1) * LDC + i] = (bf16_t)u.y;
            dst[(4 * m4 + 2) * LDC + i] = (bf16_t)u.z;
            dst[(4 * m4 + 3) * LDC + i] = (bf16_t)u.w;
        } else {                                     // fc2: [384][96] -> [96][392]
            int r = rid - 18432;
            int g = r / 24, o4 = r % 24;
            float4 u = *(const float4*)(fc2w + g * 96 + 4 * o4);
            bf16_t* dst = (bf16_t*)(ws + WS_FC2);
            dst[(4 * o4 + 0) * LDG + g] = (bf16_t)u.x;
            dst[(4 * o4 + 1) * LDG + g] = (bf16_t)u.y;
            dst[(4 * o4 + 2) * LDG + g] = (bf16_t)u.z;
            dst[(4 * o4 + 3) * LDG + g] = (bf16_t)u.w;
        }
    } else {
        int e = (blockIdx.x - 54) * 512 + tid;       // 0..12287
        if (e < 12288) {
            const float* tbl = (const float*)(ws + WS_TBL);
            float* bias = (float*)(ws + WS_BIAS);
            int h = e >> 12, nm = e & 4095, n = nm >> 6, m = nm & 63;
            int dr = (n >> 3) - (m >> 3) + 7, dc = (n & 7) - (m & 7) + 7;
            float t = tbl[(dr * 15 + dc) * 3 + h];
            bias[e] = 16.f / (1.f + __expf(-t));
        }
    }
}

// ---------------- Kernel A: fused window attention -> hs (into d_out) ----------------
// LDS 40704. Explicit 18-deep register load batches per GEMM to expose MLP.
__global__ __launch_bounds__(256, 3) void kA_attn(
    const float* __restrict__ hidden, const float* __restrict__ tv,
    const float* __restrict__ qb, const float* __restrict__ vb,
    const float* __restrict__ pb, const float* __restrict__ lsc,
    const float* __restrict__ lnww, const float* __restrict__ lnwb,
    const float* __restrict__ lnbw, const float* __restrict__ lnbb,
    const char* __restrict__ ws, float* __restrict__ hs)
{
    __shared__ __align__(16) char sm[40704];
    bf16_t* vT   = (bf16_t*)(sm + 0);         // [96][72]   = 13824
    bf16_t* qn   = (bf16_t*)(sm + 13824);     // [64][104]  = 13312
    bf16_t* kn   = (bf16_t*)(sm + 27136);     // [64][104]  = 13312 (end 40448)
    bf16_t* P    = (bf16_t*)(sm + 13824);     // [3][64][70] = 26880, overlays qn+kn (after B2)
    bf16_t* ctxb = (bf16_t*)(sm + 0);         // [64][104], overlays vT (after B4)

    const int tid = threadIdx.x;
    const int wv = tid >> 6, lane = tid & 63, lg = lane >> 4, lr = lane & 15;
    const int wid = blockIdx.x;
    const int bat = wid >> 10, wim = wid & 1023, hw = wim >> 5, wwi = wim & 31;

    // ---- phase 1: QKV; A-frags from global (rolled window), B-frags batched from ws ----
    {
        bf16x8 af[3];
        {
            int tok = 16 * wv + lr;
            int gr = ((hw << 3) + (tok >> 3) + 4) & 255;
            int gc = ((wwi << 3) + (tok & 7) + 4) & 255;
            const float* xb = hidden + (((size_t)bat << 16) + (gr << 8) + gc) * 96;
            #pragma unroll
            for (int ks = 0; ks < 3; ++ks) {
                float4 u0 = *(const float4*)(xb + 32 * ks + 8 * lg);
                float4 u1 = *(const float4*)(xb + 32 * ks + 8 * lg + 4);
                bf16x8 f;
                f[0] = (bf16_t)u0.x; f[1] = (bf16_t)u0.y; f[2] = (bf16_t)u0.z; f[3] = (bf16_t)u0.w;
                f[4] = (bf16_t)u1.x; f[5] = (bf16_t)u1.y; f[6] = (bf16_t)u1.z; f[7] = (bf16_t)u1.w;
                af[ks] = f;
            }
        }
        const bf16_t* Wq = (const bf16_t*)(ws + WS_WQ);
        const bf16_t* Wk = (const bf16_t*)(ws + WS_WK);
        const bf16_t* Wv = (const bf16_t*)(ws + WS_WV);

        // Q: 18 loads batched, then 18 MFMAs, then per-head normalize
        {
            bf16x8 wf[6][3];
            #pragma unroll
            for (int n = 0; n < 6; ++n)
                #pragma unroll
                for (int ks = 0; ks < 3; ++ks)
                    wf[n][ks] = *(const bf16x8*)(Wq + (16 * n + lr) * LDC + 32 * ks + 8 * lg);
            f32x4 acc[6];
            #pragma unroll
            for (int n = 0; n < 6; ++n) {
                f32x4 a = {0.f,0.f,0.f,0.f};
                #pragma unroll
                for (int ks = 0; ks < 3; ++ks) a = mfma16(af[ks], wf[n][ks], a);
                float bq = qb[16 * n + lr];
                #pragma unroll
                for (int j = 0; j < 4; ++j) a[j] += bq;
                acc[n] = a;
            }
            #pragma unroll
            for (int h = 0; h < 3; ++h)
                #pragma unroll
                for (int j = 0; j < 4; ++j) {
                    float s = acc[2*h][j] * acc[2*h][j] + acc[2*h+1][j] * acc[2*h+1][j];
                    s += __shfl_xor(s, 1); s += __shfl_xor(s, 2); s += __shfl_xor(s, 4); s += __shfl_xor(s, 8);
                    float inv = 1.f / fmaxf(sqrtf(s), 1e-12f);
                    int row = 16 * wv + 4 * lg + j;
                    qn[row * LDC + 32 * h + lr]      = (bf16_t)(acc[2*h][j] * inv);
                    qn[row * LDC + 32 * h + 16 + lr] = (bf16_t)(acc[2*h+1][j] * inv);
                }
        }
        // K
        {
            bf16x8 wf[6][3];
            #pragma unroll
            for (int n = 0; n < 6; ++n)
                #pragma unroll
                for (int ks = 0; ks < 3; ++ks)
                    wf[n][ks] = *(const bf16x8*)(Wk + (16 * n + lr) * LDC + 32 * ks + 8 * lg);
            f32x4 acc[6];
            #pragma unroll
            for (int n = 0; n < 6; ++n) {
                f32x4 a = {0.f,0.f,0.f,0.f};
                #pragma unroll
                for (int ks = 0; ks < 3; ++ks) a = mfma16(af[ks], wf[n][ks], a);
                acc[n] = a;
            }
            #pragma unroll
            for (int h = 0; h < 3; ++h)
                #pragma unroll
                for (int j = 0; j < 4; ++j) {
                    float s = acc[2*h][j] * acc[2*h][j] + acc[2*h+1][j] * acc[2*h+1][j];
                    s += __shfl_xor(s, 1); s += __shfl_xor(s, 2); s += __shfl_xor(s, 4); s += __shfl_xor(s, 8);
                    float inv = 1.f / fmaxf(sqrtf(s), 1e-12f);
                    int row = 16 * wv + 4 * lg + j;
                    kn[row * LDC + 32 * h + lr]      = (bf16_t)(acc[2*h][j] * inv);
                    kn[row * LDC + 32 * h + 16 + lr] = (bf16_t)(acc[2*h+1][j] * inv);
                }
        }
        // V (store transposed)
        {
            bf16x8 wf[6][3];
            #pragma unroll
            for (int n = 0; n < 6; ++n)
                #pragma unroll
                for (int ks = 0; ks < 3; ++ks)
                    wf[n][ks] = *(const bf16x8*)(Wv + (16 * n + lr) * LDC + 32 * ks + 8 * lg);
            #pragma unroll
            for (int n = 0; n < 6; ++n) {
                f32x4 a = {0.f,0.f,0.f,0.f};
                #pragma unroll
                for (int ks = 0; ks < 3; ++ks) a = mfma16(af[ks], wf[n][ks], a);
                float bv_ = vb[16 * n + lr];
                bf16x4 pk;
                #pragma unroll
                for (int j = 0; j < 4; ++j) pk[j] = (bf16_t)(a[j] + bv_);
                *(bf16x4*)(vT + (16 * n + lr) * LDT + 16 * wv + 4 * lg) = pk;
            }
        }
    }
    __syncthreads();                                         // B1

    // ---- phase 2: S = qn@kn^T (+bias+mask), softmax, write P ----
    {
        // issue all 48 bias loads first (independent of LDS), then LDS frags + MFMA
        float br[3][4][4];
        const float* biasT = (const float*)(ws + WS_BIAS);
        #pragma unroll
        for (int h = 0; h < 3; ++h)
            #pragma unroll
            for (int f = 0; f < 4; ++f)
                #pragma unroll
                for (int j = 0; j < 4; ++j)
                    br[h][f][j] = biasT[(h << 12) + (16 * wv + 4 * lg + j) * 64 + 16 * f + lr];

        f32x4 s[3][4];
        #pragma unroll
        for (int h = 0; h < 3; ++h) {
            bf16x8 aq = *(const bf16x8*)(qn + (16 * wv + lr) * LDC + 32 * h + 8 * lg);
            bf16x8 bk[4];
            #pragma unroll
            for (int f = 0; f < 4; ++f)
                bk[f] = *(const bf16x8*)(kn + (16 * f + lr) * LDC + 32 * h + 8 * lg);
            #pragma unroll
            for (int f = 0; f < 4; ++f) {
                f32x4 z = {0.f,0.f,0.f,0.f};
                s[h][f] = mfma16(aq, bk[f], z);
            }
        }
        __syncthreads();                                     // B2: qn/kn reads done, P may overlay

        float ls[3];
        #pragma unroll
        for (int h = 0; h < 3; ++h) ls[h] = __expf(fminf(lsc[h], 4.6051702f));
        int cntm[4], cnti[4];
        #pragma unroll
        for (int f = 0; f < 4; ++f) cntm[f] = regcnt(16 * f + lr, hw, wwi);
        #pragma unroll
        for (int j = 0; j < 4; ++j) cnti[j] = regcnt(16 * wv + 4 * lg + j, hw, wwi);
        #pragma unroll
        for (int h = 0; h < 3; ++h) {
            #pragma unroll
            for (int f = 0; f < 4; ++f)
                #pragma unroll
                for (int j = 0; j < 4; ++j) {
                    float mk = (cnti[j] != cntm[f]) ? -100.f : 0.f;
                    s[h][f][j] = fmaf(s[h][f][j], ls[h], br[h][f][j] + mk);
                }
            #pragma unroll
            for (int j = 0; j < 4; ++j) {
                float mx = fmaxf(fmaxf(s[h][0][j], s[h][1][j]), fmaxf(s[h][2][j], s[h][3][j]));
                mx = fmaxf(mx, __shfl_xor(mx, 1)); mx = fmaxf(mx, __shfl_xor(mx, 2));
                mx = fmaxf(mx, __shfl_xor(mx, 4)); mx = fmaxf(mx, __shfl_xor(mx, 8));
                float sum = 0.f;
                #pragma unroll
                for (int f = 0; f < 4; ++f) { float e = __expf(s[h][f][j] - mx); s[h][f][j] = e; sum += e; }
                sum += __shfl_xor(sum, 1); sum += __shfl_xor(sum, 2); sum += __shfl_xor(sum, 4); sum += __shfl_xor(sum, 8);
                float inv = 1.f / sum;
                int row = 16 * wv + 4 * lg + j;
                #pragma unroll
                for (int f = 0; f < 4; ++f)
                    P[h * 64 * LDP + row * LDP + 16 * f + lr] = (bf16_t)(s[h][f][j] * inv);
            }
        }
    }
    __syncthreads();                                         // B3: P written

    // ---- phase 3: ctx = P@V ----
    {
        f32x4 ctx[6];
        #pragma unroll
        for (int t = 0; t < 6; ++t) { f32x4 z = {0.f,0.f,0.f,0.f}; ctx[t] = z; }
        bf16x8 ap[3][2], bv2[3][2][2];
        #pragma unroll
        for (int h = 0; h < 3; ++h)
            #pragma unroll
            for (int ks = 0; ks < 2; ++ks) {
                ap[h][ks] = *(const bf16x8*)(P + h * 64 * LDP + (16 * wv + lr) * LDP + 32 * ks + 8 * lg);
                #pragma unroll
                for (int dt = 0; dt < 2; ++dt)
                    bv2[h][dt][ks] = *(const bf16x8*)(vT + (32 * h + 16 * dt + lr) * LDT + 32 * ks + 8 * lg);
            }
        #pragma unroll
        for (int h = 0; h < 3; ++h)
            #pragma unroll
            for (int ks = 0; ks < 2; ++ks)
                #pragma unroll
                for (int dt = 0; dt < 2; ++dt)
                    ctx[2 * h + dt] = mfma16(ap[h][ks], bv2[h][dt][ks], ctx[2 * h + dt]);
        __syncthreads();                                     // B4: all P/vT reads done
        #pragma unroll
        for (int t = 0; t < 6; ++t)
            #pragma unroll
            for (int j = 0; j < 4; ++j)
                ctxb[(16 * wv + 4 * lg + j) * LDC + 16 * t + lr] = (bf16_t)ctx[t][j];
    }
    __syncthreads();                                         // B5

    // ---- phase 4: proj (batched B) + conditional LN + residual -> hs ----
    {
        const bf16_t* Wp = (const bf16_t*)(ws + WS_WP);
        bf16x8 wf[6][3];
        #pragma unroll
        for (int n = 0; n < 6; ++n)
            #pragma unroll
            for (int ks = 0; ks < 3; ++ks)
                wf[n][ks] = *(const bf16x8*)(Wp + (16 * n + lr) * LDC + 32 * ks + 8 * lg);
        bf16x8 af[3];
        #pragma unroll
        for (int ks = 0; ks < 3; ++ks) af[ks] = *(const bf16x8*)(ctxb + (16 * wv + lr) * LDC + 32 * ks + 8 * lg);
        f32x4 acc[6];
        #pragma unroll
        for (int n = 0; n < 6; ++n) {
            f32x4 a = {0.f,0.f,0.f,0.f};
            #pragma unroll
            for (int ks = 0; ks < 3; ++ks) a = mfma16(af[ks], wf[n][ks], a);
            float bp = pb[16 * n + lr];
            #pragma unroll
            for (int j = 0; j < 4; ++j) a[j] += bp;
            acc[n] = a;
        }
        float tb = tv[bat];
        float wco[6], bco[6];
        #pragma unroll
        for (int t = 0; t < 6; ++t) {
            int col = 16 * t + lr;
            wco[t] = fmaf(tb, lnww[col], lnwb[col]);
            bco[t] = fmaf(tb, lnbw[col], lnbb[col]);
        }
        #pragma unroll
        for (int j = 0; j < 4; ++j) {
            float smn = 0.f, sq = 0.f;
            #pragma unroll
            for (int t = 0; t < 6; ++t) { float v = acc[t][j]; smn += v; sq = fmaf(v, v, sq); }
            smn += __shfl_xor(smn, 1); smn += __shfl_xor(smn, 2); smn += __shfl_xor(smn, 4); smn += __shfl_xor(smn, 8);
            sq  += __shfl_xor(sq, 1);  sq  += __shfl_xor(sq, 2);  sq  += __shfl_xor(sq, 4);  sq  += __shfl_xor(sq, 8);
            float mean = smn * (1.f / 96.f);
            float var  = sq * (1.f / 96.f) - mean * mean;
            float rstd = rsqrtf(var + 1e-5f);
            int trow = 16 * wv + 4 * lg + j;
            int gr = ((hw << 3) + (trow >> 3) + 4) & 255;
            int gc = ((wwi << 3) + (trow & 7) + 4) & 255;
            size_t gbase = (((size_t)bat << 16) + (gr << 8) + gc) * 96;
            float hid[6];
            #pragma unroll
            for (int t = 0; t < 6; ++t) hid[t] = hidden[gbase + 16 * t + lr];
            #pragma unroll
            for (int t = 0; t < 6; ++t) {
                float xn = (acc[t][j] - mean) * rstd;
                hs[gbase + 16 * t + lr] = hid[t] + fmaf(wco[t], xn, bco[t]);
            }
        }
    }
}

// ---------------- Kernel B: MLP + conditional LN + residual (in-place on d_out) ----------------
// Explicit register batches: fc1 in 4 groups of 18 loads; fc2 in 6 groups of 14.
__global__ __launch_bounds__(256, 3) void kB_mlp(
    const float* __restrict__ tv, const float* __restrict__ fc1b,
    const float* __restrict__ fc2b,
    const float* __restrict__ lnww, const float* __restrict__ lnwb,
    const float* __restrict__ lnbw, const float* __restrict__ lnbb,
    const char* __restrict__ ws, float* __restrict__ io)
{
    __shared__ __align__(16) bf16_t gbuf[64 * LDG];   // 50176 B

    const int tid = threadIdx.x;
    const int wv = tid >> 6, lane = tid & 63, lg = lane >> 4, lr = lane & 15;
    const size_t t0 = (size_t)blockIdx.x * 64;

    bf16x8 hf[3];
    #pragma unroll
    for (int ks = 0; ks < 3; ++ks) {
        const float* p = io + (t0 + 16 * wv + lr) * 96 + 32 * ks + 8 * lg;
        float4 u0 = *(const float4*)p;
        float4 u1 = *(const float4*)(p + 4);
        bf16x8 f;
        f[0] = (bf16_t)u0.x; f[1] = (bf16_t)u0.y; f[2] = (bf16_t)u0.z; f[3] = (bf16_t)u0.w;
        f[4] = (bf16_t)u1.x; f[5] = (bf16_t)u1.y; f[6] = (bf16_t)u1.z; f[7] = (bf16_t)u1.w;
        hf[ks] = f;
    }

    const bf16_t* w1 = (const bf16_t*)(ws + WS_FC1);
    const bf16_t* w2 = (const bf16_t*)(ws + WS_FC2);

    // fc1 + gelu: 4 groups × (18 batched loads -> 18 MFMA -> gelu -> LDS)
    #pragma unroll
    for (int g = 0; g < 4; ++g) {
        bf16x8 wf[6][3];
        #pragma unroll
        for (int n = 0; n < 6; ++n)
            #pragma unroll
            for (int ks = 0; ks < 3; ++ks)
                wf[n][ks] = *(const bf16x8*)(w1 + (16 * (6 * g + n) + lr) * LDC + 32 * ks + 8 * lg);
        #pragma unroll
        for (int n = 0; n < 6; ++n) {
            int nt = 6 * g + n;
            f32x4 a = {0.f,0.f,0.f,0.f};
            #pragma unroll
            for (int ks = 0; ks < 3; ++ks) a = mfma16(hf[ks], wf[n][ks], a);
            float bb = fc1b[16 * nt + lr];
            #pragma unroll
            for (int j = 0; j < 4; ++j) {
                float x = a[j] + bb;
                float u = 0.7978845608f * fmaf(0.044715f * x, x * x, x);
                float t = __expf(2.f * u);
                float g2 = x - x * __builtin_amdgcn_rcpf(t + 1.f);
                gbuf[(16 * wv + 4 * lg + j) * LDG + 16 * nt + lr] = (bf16_t)g2;
            }
        }
    }
    __syncthreads();                                  // the only barrier

    // fc2: 6 groups × (2 LDS reads + 12 batched weight loads -> 12 MFMA)
    f32x4 mlp[6];
    #pragma unroll
    for (int t = 0; t < 6; ++t) { f32x4 z = {0.f,0.f,0.f,0.f}; mlp[t] = z; }
    #pragma unroll
    for (int g = 0; g < 6; ++g) {
        bf16x8 gf[2], wf2[2][6];
        #pragma unroll
        for (int u = 0; u < 2; ++u) {
            int kk = 2 * g + u;
            gf[u] = *(const bf16x8*)(gbuf + (16 * wv + lr) * LDG + 32 * kk + 8 * lg);
            #pragma unroll
            for (int n = 0; n < 6; ++n)
                wf2[u][n] = *(const bf16x8*)(w2 + (16 * n + lr) * LDG + 32 * kk + 8 * lg);
        }
        #pragma unroll
        for (int u = 0; u < 2; ++u)
            #pragma unroll
            for (int n = 0; n < 6; ++n)
                mlp[n] = mfma16(gf[u], wf2[u][n], mlp[n]);
    }

    float tb = tv[t0 >> 16];
    float wco[6], bco[6];
    #pragma unroll
    for (int t = 0; t < 6; ++t) {
        int col = 16 * t + lr;
        wco[t] = fmaf(tb, lnww[col], lnwb[col]);
        bco[t] = fmaf(tb, lnbw[col], lnbb[col]);
        mlp[t][0] += fc2b[col]; mlp[t][1] += fc2b[col]; mlp[t][2] += fc2b[col]; mlp[t][3] += fc2b[col];
    }
    #pragma unroll
    for (int j = 0; j < 4; ++j) {
        float smn = 0.f, sq = 0.f;
        #pragma unroll
        for (int t = 0; t < 6; ++t) { float v = mlp[t][j]; smn += v; sq = fmaf(v, v, sq); }
        smn += __shfl_xor(smn, 1); smn += __shfl_xor(smn, 2); smn += __shfl_xor(smn, 4); smn += __shfl_xor(smn, 8);
        sq  += __shfl_xor(sq, 1);  sq  += __shfl_xor(sq, 2);  sq  += __shfl_xor(sq, 4);  sq  += __shfl_xor(sq, 8);
        float mean = smn * (1.f / 96.f);
        float var  = sq * (1.f / 96.f) - mean * mean;
        float rstd = rsqrtf(var + 1e-5f);
        size_t row = t0 + 16 * wv + 4 * lg + j;
        float hid[6];
        #pragma unroll
        for (int t = 0; t < 6; ++t) hid[t] = io[row * 96 + 16 * t + lr];
        #pragma unroll
        for (int t = 0; t < 6; ++t) {
            float xn = (mlp[t][j] - mean) * rstd;
            io[row * 96 + 16 * t + lr] = hid[t] + fmaf(wco[t], xn, bco[t]);
        }
    }
}

extern "C" void kernel_launch(void* const* d_in, const int* in_sizes, int n_in,
                              void* d_out, int out_size, void* d_ws, size_t ws_size,
                              hipStream_t stream)
{
    const float* hidden = (const float*)d_in[0];
    const float* tv     = (const float*)d_in[1];
    const float* q_w    = (const float*)d_in[2];
    const float* q_b    = (const float*)d_in[3];
    const float* k_w    = (const float*)d_in[4];
    const float* v_w    = (const float*)d_in[5];
    const float* v_b    = (const float*)d_in[6];
    const float* p_w    = (const float*)d_in[7];
    const float* p_b    = (const float*)d_in[8];
    const float* lsc    = (const float*)d_in[9];
    const float* cw1    = (const float*)d_in[10];
    const float* cb1    = (const float*)d_in[11];
    const float* cw2    = (const float*)d_in[12];
    const float* lnb_ww = (const float*)d_in[13];
    const float* lnb_wb = (const float*)d_in[14];
    const float* lnb_bw = (const float*)d_in[15];
    const float* lnb_bb = (const float*)d_in[16];
    const float* lna_ww = (const float*)d_in[17];
    const float* lna_wb = (const float*)d_in[18];
    const float* lna_bw = (const float*)d_in[19];
    const float* lna_bb = (const float*)d_in[20];
    const float* fc1_w  = (const float*)d_in[21];
    const float* fc1_b  = (const float*)d_in[22];
    const float* fc2_w  = (const float*)d_in[23];
    const float* fc2_b  = (const float*)d_in[24];
    char* ws = (char*)d_ws;
    float* out = (float*)d_out;

    k0a_cpb<<<dim3(57), dim3(256), 0, stream>>>(cw1, cb1, cw2, ws);
    k0w_prep<<<dim3(78), dim3(512), 0, stream>>>(q_w, k_w, v_w, p_w, fc1_w, fc2_w, ws);
    kA_attn<<<dim3(2048), dim3(256), 0, stream>>>(hidden, tv, q_b, v_b, p_b, lsc,
                                                  lnb_ww, lnb_wb, lnb_bw, lnb_bb, ws, out);
    kB_mlp<<<dim3(2048), dim3(256), 0, stream>>>(tv, fc1_b, fc2_b,
                                                 lna_ww, lna_wb, lna_bw, lna_bb, ws, out);
}